// Round 21
// baseline (71.593 us; speedup 1.0000x reference)
//
#include <hip/hip_runtime.h>
#include <hip/hip_bf16.h>

// Problem constants
#define NN      2048
#define NODES   64
#define DIN     4
#define DOUT    4
#define MM      128
#define DEG     8
#define PP      32
#define JITTER  1e-4f

typedef __attribute__((ext_vector_type(8))) short short8;
typedef __attribute__((ext_vector_type(4))) float f32x4;
typedef __attribute__((ext_vector_type(4))) unsigned short bf16x4;

// Hbuf per-node layout (4 tiles of 16384 bf16): M0 M1 M2 M3
#define HSTRIDE 65536

__device__ __forceinline__ unsigned short f2b(float f) {
    union { float f; unsigned int u; } v; v.f = f;
    unsigned int u = v.u;
    u += 0x7fffu + ((u >> 16) & 1u);
    return (unsigned short)(u >> 16);
}
__device__ __forceinline__ float b2f(unsigned short h) {
    union { unsigned int u; float f; } v; v.u = ((unsigned int)h) << 16;
    return v.f;
}
// pack 2x f32x4 -> short8 (bf16 rne), accumulating sum of squares of ROUNDED vals
__device__ __forceinline__ short8 pack8(f32x4 a, f32x4 b, float& sq) {
    short8 r;
    #pragma unroll
    for (int e = 0; e < 4; e++) {
        unsigned short ha = f2b(a[e]), hb = f2b(b[e]);
        float fa = b2f(ha), fb = b2f(hb);
        sq += fa * fa + fb * fb;
        r[e] = (short)ha; r[e + 4] = (short)hb;
    }
    return r;
}

// async global->LDS, 16B per lane. LDS dest = wave-uniform base + lane*16.
__device__ __forceinline__ void gload16(const unsigned short* g, unsigned short* l) {
    __builtin_amdgcn_global_load_lds(
        (const __attribute__((address_space(1))) unsigned int*)g,
        (__attribute__((address_space(3))) unsigned int*)l, 16, 0, 0);
}

// ---------------- K1: fused NS + W + M_d (one block per (node,d)) -----------
// 256 blocks x 512 threads. Each block: D = Ku-I (register-direct MFMA),
// S = D^2, DS = D^3 -> Kinv = I-D+S-DS kept IN LDS (SA); W^T = qmu^T@Kinv
// (d==0 only); G_d = Lq_d^T @ Kinv (Lq staged into dead SB); GT stored back
// to SB transposed; M_d = GT@GT^T - Kinv -> Hbuf tile d.
// var_d = 1 + k^T M_d k absorbs the old R/t-term tile.
__global__ __launch_bounds__(512) void k_nsgt(const float* __restrict__ Z,
                                              const int* __restrict__ pa,
                                              const float* __restrict__ qmu,
                                              const float* __restrict__ qsqrt,
                                              unsigned short* __restrict__ Wbf,
                                              unsigned short* __restrict__ Hbuf,
                                              unsigned short* __restrict__ Zpan,
                                              float* __restrict__ zsqg) {
    __shared__ unsigned short SA[16384];  // D -> Kinv (bf16, swizzled)
    __shared__ unsigned short SB[16384];  // S -> qmuT -> Lq -> GT
    __shared__ float zsqs[128];
    __shared__ int cols[32];
    int bid = blockIdx.x, t = threadIdx.x;
    int node = (bid & 7) + 8 * (bid >> 5);   // node's 4 d-blocks on one XCD
    int d = (bid >> 3) & 3;
    int wv = t >> 6, ln = t & 63;
    if (t < 32) cols[t] = pa[node * 32 + t];
    __syncthreads();

    int wmI = wv & 1, wnI = wv >> 1;      // 2 x 4 wave grid
    int wm = wmI * 64, wn = wnI * 32;
    int lr = ln & 15, lk = ln >> 4;
    int cg0 = cols[lk * 8], cg1 = cols[lk * 8 + 4];

    short8 zv[4], xv[2];
    #pragma unroll
    for (int mi = 0; mi < 4; mi++) {
        int m = wm + mi * 16 + lr;
        float sq = 0.f;
        zv[mi] = pack8(*(const f32x4*)(Z + (size_t)m * 256 + cg0),
                       *(const f32x4*)(Z + (size_t)m * 256 + cg1), sq);
        sq += __shfl_xor(sq, 16);
        sq += __shfl_xor(sq, 32);
        if (lk == 0) zsqs[m] = sq;
        if (d == 0 && wnI == 0)
            *(short8*)(Zpan + (size_t)node * 4096 + (size_t)m * 32 + lk * 8) = zv[mi];
    }
    #pragma unroll
    for (int ni = 0; ni < 2; ni++) {
        int x = wn + ni * 16 + lr;
        float sq = 0.f;
        xv[ni] = pack8(*(const f32x4*)(Z + (size_t)x * 256 + cg0),
                       *(const f32x4*)(Z + (size_t)x * 256 + cg1), sq);
    }
    __syncthreads();
    if (d == 0 && t < 128) zsqg[node * 128 + t] = zsqs[t];

    f32x4 dacc[4][2] = {};
    #pragma unroll
    for (int mi = 0; mi < 4; mi++)
        #pragma unroll
        for (int ni = 0; ni < 2; ni++)
            dacc[mi][ni] = __builtin_amdgcn_mfma_f32_16x16x32_bf16(zv[mi], xv[ni], dacc[mi][ni], 0, 0, 0);

    #pragma unroll
    for (int mi = 0; mi < 4; mi++) {
        int mb = wm + mi * 16 + lk * 4;
        f32x4 zs4 = *(const f32x4*)(zsqs + mb);
        #pragma unroll
        for (int ni = 0; ni < 2; ni++) {
            int x = wn + ni * 16 + lr;
            float xs = zsqs[x];
            bf16x4 kv4;
            #pragma unroll
            for (int j = 0; j < 4; j++) {
                float sq = fmaxf(zs4[j] + xs - 2.0f * dacc[mi][ni][j], 0.0f);
                float v = (mb + j == x) ? JITTER : __expf(-0.5f * sq);
                kv4[j] = f2b(v);
            }
            *(bf16x4*)(SA + x * 128 + (((mb >> 3) ^ (x & 7)) * 8) + (mb & 7)) = kv4;
        }
    }
    __syncthreads();

    // GEMM1: S = D @ D^T
    f32x4 acc1[4][2] = {};
    #pragma unroll
    for (int ks = 0; ks < 4; ks++) {
        int seg = ks * 4 + lk;
        short8 av[4], bv[2];
        #pragma unroll
        for (int mi = 0; mi < 4; mi++) {
            int r = wm + mi * 16 + lr;
            av[mi] = *(const short8*)(SA + r * 128 + ((seg ^ (r & 7)) * 8));
        }
        #pragma unroll
        for (int ni = 0; ni < 2; ni++) {
            int x = wn + ni * 16 + lr;
            bv[ni] = *(const short8*)(SA + x * 128 + ((seg ^ (x & 7)) * 8));
        }
        #pragma unroll
        for (int mi = 0; mi < 4; mi++)
            #pragma unroll
            for (int ni = 0; ni < 2; ni++)
                acc1[mi][ni] = __builtin_amdgcn_mfma_f32_16x16x32_bf16(av[mi], bv[ni], acc1[mi][ni], 0, 0, 0);
    }
    #pragma unroll
    for (int mi = 0; mi < 4; mi++)
        #pragma unroll
        for (int ni = 0; ni < 2; ni++)
            #pragma unroll
            for (int j = 0; j < 4; j++) {
                int rr = wm + mi * 16 + lk * 4 + j;
                int cc = wn + ni * 16 + lr;
                SB[rr * 128 + (((cc >> 3) ^ (rr & 7)) * 8) + (cc & 7)] = f2b(acc1[mi][ni][j]);
            }
    __syncthreads();

    // GEMM2: DS = D @ S^T
    f32x4 acc2[4][2] = {};
    #pragma unroll
    for (int ks = 0; ks < 4; ks++) {
        int seg = ks * 4 + lk;
        short8 av[4], bv[2];
        #pragma unroll
        for (int mi = 0; mi < 4; mi++) {
            int r = wm + mi * 16 + lr;
            av[mi] = *(const short8*)(SA + r * 128 + ((seg ^ (r & 7)) * 8));
        }
        #pragma unroll
        for (int ni = 0; ni < 2; ni++) {
            int x = wn + ni * 16 + lr;
            bv[ni] = *(const short8*)(SB + x * 128 + ((seg ^ (x & 7)) * 8));
        }
        #pragma unroll
        for (int mi = 0; mi < 4; mi++)
            #pragma unroll
            for (int ni = 0; ni < 2; ni++)
                acc2[mi][ni] = __builtin_amdgcn_mfma_f32_16x16x32_bf16(av[mi], bv[ni], acc2[mi][ni], 0, 0, 0);
    }
    __syncthreads();

    // Kinv = I - D + S - DS -> SA (in place, stays in LDS)
    #pragma unroll
    for (int mi = 0; mi < 4; mi++)
        #pragma unroll
        for (int ni = 0; ni < 2; ni++)
            #pragma unroll
            for (int j = 0; j < 4; j++) {
                int rr = wm + mi * 16 + lk * 4 + j;
                int cc = wn + ni * 16 + lr;
                int sw = rr * 128 + (((cc >> 3) ^ (rr & 7)) * 8) + (cc & 7);
                float dv = b2f(SA[sw]);
                float eye = (rr == cc) ? 1.0f : 0.0f;
                float kinv = eye - dv + acc1[mi][ni][j] - acc2[mi][ni][j];
                SA[sw] = f2b(kinv);
            }
    if (d == 0) {
        for (int q = t; q < 2048; q += 512) {
            int dd = q >> 7, mm = q & 127;
            unsigned short val = 0;
            if (dd < 4) val = f2b(qmu[mm * 256 + node * 4 + dd]);
            SB[dd * 128 + (((mm >> 3) ^ (dd & 7)) * 8) + (mm & 7)] = val;
        }
    }
    __syncthreads();

    if (d == 0) {
        // W^T = qmuT @ Kinv (16 x 128); wave wv owns cols wv*16..+15
        f32x4 wacc = {};
        #pragma unroll
        for (int ks = 0; ks < 4; ks++) {
            int seg = ks * 4 + lk;
            short8 aq = *(const short8*)(SB + lr * 128 + ((seg ^ (lr & 7)) * 8));
            int x = wv * 16 + lr;
            short8 bk = *(const short8*)(SA + x * 128 + ((seg ^ (x & 7)) * 8));
            wacc = __builtin_amdgcn_mfma_f32_16x16x32_bf16(aq, bk, wacc, 0, 0, 0);
        }
        unsigned short* Wg = Wbf + (size_t)node * 2048;
        #pragma unroll
        for (int j = 0; j < 4; j++) {
            int dd = lk * 4 + j;
            int mm = wv * 16 + lr;
            Wg[dd * 128 + (((mm >> 3) ^ (dd & 7)) * 8) + (mm & 7)] = f2b(wacc[j]);
        }
    }
    __syncthreads();   // W's SB reads done before Lq overwrites SB

    // stage Lq_d tril (fp32 -> bf16, transposed+masked, swizzled) into SB
    {
        const float* Lq = qsqrt + (size_t)(node * 4 + d) * 16384;
        int m = t & 127, ph = t >> 7;
        for (int pp = 0; pp < 32; pp++) {
            int p = ph * 32 + pp;
            float v = 0.f;
            if (p >= m) v = Lq[p * 128 + m];
            SB[m * 128 + (((p >> 3) ^ (m & 7)) * 8) + (p & 7)] = f2b(v);
        }
    }
    __syncthreads();

    // G_d = Lq_d^T @ Kinv  (A = SB (Lq^T), B = SA (Kinv, symmetric))
    f32x4 gacc[4][2] = {};
    #pragma unroll
    for (int ks = 0; ks < 4; ks++) {
        int seg = ks * 4 + lk;
        short8 av[4], bv[2];
        #pragma unroll
        for (int mi = 0; mi < 4; mi++) {
            int r = wm + mi * 16 + lr;
            av[mi] = *(const short8*)(SB + r * 128 + ((seg ^ (r & 7)) * 8));
        }
        #pragma unroll
        for (int ni = 0; ni < 2; ni++) {
            int x = wn + ni * 16 + lr;
            bv[ni] = *(const short8*)(SA + x * 128 + ((seg ^ (x & 7)) * 8));
        }
        #pragma unroll
        for (int mi = 0; mi < 4; mi++)
            #pragma unroll
            for (int ni = 0; ni < 2; ni++)
                gacc[mi][ni] = __builtin_amdgcn_mfma_f32_16x16x32_bf16(av[mi], bv[ni], gacc[mi][ni], 0, 0, 0);
    }
    __syncthreads();   // all Lq reads of SB done before GT overwrites it

    // store G TRANSPOSED into SB: GT[i=G-col][m=G-row], swizzled
    #pragma unroll
    for (int mi = 0; mi < 4; mi++)
        #pragma unroll
        for (int ni = 0; ni < 2; ni++)
            #pragma unroll
            for (int j = 0; j < 4; j++) {
                int rr = wm + mi * 16 + lk * 4 + j;   // G row (m)
                int cc = wn + ni * 16 + lr;           // G col (i)
                SB[cc * 128 + (((rr >> 3) ^ (cc & 7)) * 8) + (rr & 7)] = f2b(gacc[mi][ni][j]);
            }
    __syncthreads();

    // M_d = GT @ GT^T - Kinv  (= G^T G - Kinv, symmetric) -> Hbuf tile d
    f32x4 macc[4][2] = {};
    #pragma unroll
    for (int ks = 0; ks < 4; ks++) {
        int seg = ks * 4 + lk;
        short8 av[4], bv[2];
        #pragma unroll
        for (int mi = 0; mi < 4; mi++) {
            int r = wm + mi * 16 + lr;
            av[mi] = *(const short8*)(SB + r * 128 + ((seg ^ (r & 7)) * 8));
        }
        #pragma unroll
        for (int ni = 0; ni < 2; ni++) {
            int x = wn + ni * 16 + lr;
            bv[ni] = *(const short8*)(SB + x * 128 + ((seg ^ (x & 7)) * 8));
        }
        #pragma unroll
        for (int mi = 0; mi < 4; mi++)
            #pragma unroll
            for (int ni = 0; ni < 2; ni++)
                macc[mi][ni] = __builtin_amdgcn_mfma_f32_16x16x32_bf16(av[mi], bv[ni], macc[mi][ni], 0, 0, 0);
    }
    unsigned short* Mg = Hbuf + (size_t)node * HSTRIDE + (size_t)d * 16384;
    #pragma unroll
    for (int mi = 0; mi < 4; mi++)
        #pragma unroll
        for (int ni = 0; ni < 2; ni++)
            #pragma unroll
            for (int j = 0; j < 4; j++) {
                int rr = wm + mi * 16 + lk * 4 + j;
                int cc = wn + ni * 16 + lr;
                int sw = rr * 128 + (((cc >> 3) ^ (rr & 7)) * 8) + (cc & 7);
                float mval = macc[mi][ni][j] - b2f(SA[sw]);
                Mg[sw] = f2b(mval);
            }
}

// ---------------- K2: tiles-outer k_main, 4 M-tiles + kreg dot epilogue -----
__global__ __launch_bounds__(512, 1) void k_main(const float* __restrict__ X,
                                                 const unsigned short* __restrict__ Zpan,
                                                 const float* __restrict__ zsqg,
                                                 const int* __restrict__ pa,
                                                 const unsigned short* __restrict__ Hbuf,
                                                 const unsigned short* __restrict__ Wbf,
                                                 float* __restrict__ out) {
    __shared__ unsigned short A0[16384];
    __shared__ unsigned short A1[16384];   // phase 1: 8 wave strips (4KB each)

    int bid = blockIdx.x;
    int node = (bid & 7) + 8 * (bid >> 6);   // node's 8 blocks on one XCD
    int half = (bid >> 3) & 7;
    int x0 = half * 256;
    int t = threadIdx.x;
    int wv = t >> 6, ln = t & 63;
    int lr = ln & 15, lk = ln >> 4;

    const unsigned short* Asrc = Hbuf + (size_t)node * HSTRIDE;
    const unsigned short* Wsrc = Wbf + (size_t)node * 2048;
    int cg0 = pa[node * 32 + lk * 8];
    int cg1 = pa[node * 32 + lk * 8 + 4];

    unsigned short* strip = A1 + wv * 2048;   // wave-private, dead before tile1

    // Z fragments: coalesced b128 from the precomputed panel (L2-hot)
    const unsigned short* Zp = Zpan + (size_t)node * 4096;
    short8 zv[8];
    #pragma unroll
    for (int mi = 0; mi < 8; mi++)
        zv[mi] = *(const short8*)(Zp + (size_t)(mi * 16 + lr) * 32 + lk * 8);
    // issue tile0 -> A0 early (hides under phase 1); 4 gloads per wave
    #pragma unroll
    for (int i = 0; i < 4; i++) {
        int ch = i * 8 + wv;
        gload16(Asrc + ch * 512 + ln * 8, A0 + ch * 512);
    }
    // W fragments once (global, pre-swizzled)
    short8 aw[4];
    #pragma unroll
    for (int ks = 0; ks < 4; ks++)
        aw[ks] = *(const short8*)(Wsrc + lr * 128 + (((ks * 4 + lk) ^ (lr & 7)) * 8));

    // ---- phase 1: 2 col-groups -> bvAll + kreg (registers) + mean ----
    const float* Xb = X + (size_t)(x0 + wv * 32 + lr) * 256;
    const float* zsq_n = zsqg + node * 128;
    f32x4 xr0 = *(const f32x4*)(Xb + cg0);
    f32x4 xr1 = *(const f32x4*)(Xb + cg1);
    short8 bvAll[2][4];
    bf16x4 kreg[8][2];     // k rows (mi*16+lk*4+j), col x — matches acc C-layout
    f32x4 maccA[2];
    #pragma unroll
    for (int it = 0; it < 2; it++) {
        float xs = 0.f;
        short8 xv = pack8(xr0, xr1, xs);
        xs += __shfl_xor(xs, 16);
        xs += __shfl_xor(xs, 32);
        if (it < 1) {   // next col-group = +16 rows of X
            xr0 = *(const f32x4*)(Xb + 4096 + cg0);
            xr1 = *(const f32x4*)(Xb + 4096 + cg1);
        }
        f32x4 dacc[8] = {};
        #pragma unroll
        for (int mi = 0; mi < 8; mi++)
            dacc[mi] = __builtin_amdgcn_mfma_f32_16x16x32_bf16(zv[mi], xv, dacc[mi], 0, 0, 0);
        #pragma unroll
        for (int mi = 0; mi < 8; mi++) {
            int mb = mi * 16 + lk * 4;
            f32x4 zs4 = *(const f32x4*)(zsq_n + mb);
            bf16x4 kv4;
            #pragma unroll
            for (int j = 0; j < 4; j++) {
                float sq = fmaxf(zs4[j] + xs - 2.0f * dacc[mi][j], 0.0f);
                kv4[j] = f2b(__expf(-0.5f * sq));
            }
            kreg[mi][it] = kv4;
            *(bf16x4*)(strip + lr * 128 + (((mb >> 3) ^ (lr & 7)) * 8) + (mb & 7)) = kv4;
        }
        #pragma unroll
        for (int ks = 0; ks < 4; ks++)
            bvAll[it][ks] = *(const short8*)(strip + lr * 128 + (((ks * 4 + lk) ^ (lr & 7)) * 8));
        f32x4 m4 = {};
        #pragma unroll
        for (int ks = 0; ks < 4; ks++)
            m4 = __builtin_amdgcn_mfma_f32_16x16x32_bf16(aw[ks], bvAll[it][ks], m4, 0, 0, 0);
        maccA[it] = m4;
    }

    // ---- phase 2: 4 M-tiles, staged once; dot-with-k epilogue ----
    float vout[4][2];
    #pragma unroll
    for (int tt = 0; tt < 4; tt++) {
        unsigned short* cbuf = (tt & 1) ? A1 : A0;
        __syncthreads();   // tile tt landed (vmcnt drained); strips/prev reads done
        if (tt < 3) {
            const unsigned short* ns = Asrc + (size_t)(tt + 1) * 16384;
            unsigned short* nb = (tt & 1) ? A0 : A1;
            #pragma unroll
            for (int i = 0; i < 4; i++) {
                int ch = i * 8 + wv;
                gload16(ns + ch * 512 + ln * 8, nb + ch * 512);
            }
        }
        float ssum[2] = {0.f, 0.f};
        __builtin_amdgcn_s_setprio(1);
        #pragma unroll
        for (int mi = 0; mi < 8; mi++) {
            int r = mi * 16 + lr;
            f32x4 a4[2] = {};
            #pragma unroll
            for (int ks = 0; ks < 4; ks++) {
                short8 av = *(const short8*)(cbuf + r * 128 + (((ks * 4 + lk) ^ (r & 7)) * 8));
                #pragma unroll
                for (int it = 0; it < 2; it++)
                    a4[it] = __builtin_amdgcn_mfma_f32_16x16x32_bf16(av, bvAll[it][ks], a4[it], 0, 0, 0);
            }
            #pragma unroll
            for (int it = 0; it < 2; it++)
                #pragma unroll
                for (int j = 0; j < 4; j++)
                    ssum[it] += a4[it][j] * b2f(kreg[mi][it][j]);
        }
        __builtin_amdgcn_s_setprio(0);
        #pragma unroll
        for (int it = 0; it < 2; it++) {
            float sv = ssum[it];
            sv += __shfl_xor(sv, 16);
            sv += __shfl_xor(sv, 32);
            vout[tt][it] = sv;
        }
    }

    // ---- output ----
    if (lk == 0) {
        #pragma unroll
        for (int it = 0; it < 2; it++) {
            int x = x0 + wv * 32 + it * 16 + lr;
            f32x4 mv, vv;
            #pragma unroll
            for (int j = 0; j < 4; j++) {
                mv[j] = maccA[it][j];
                vv[j] = 1.0f + vout[j][it];
            }
            *(f32x4*)(out + (size_t)x * 256 + node * 4) = mv;
            *(f32x4*)(out + 524288 + (size_t)x * 256 + node * 4) = vv;
        }
    }
}

extern "C" void kernel_launch(void* const* d_in, const int* in_sizes, int n_in,
                              void* d_out, int out_size, void* d_ws, size_t ws_size,
                              hipStream_t stream) {
    const float* X = (const float*)d_in[0];
    const float* Z = (const float*)d_in[1];
    const float* qmu = (const float*)d_in[2];
    const float* qsqrt = (const float*)d_in[3];
    const int* pa = (const int*)d_in[4];
    float* out = (float*)d_out;

    char* ws = (char*)d_ws;
    size_t off = 0;
    unsigned short* Wbf = (unsigned short*)(ws + off);   off += 131072ull * 2;   // 256 KB
    unsigned short* Hbuf = (unsigned short*)(ws + off);  off += 4194304ull * 2;  // 8 MB
    unsigned short* Zpan = (unsigned short*)(ws + off);  off += 262144ull * 2;   // 512 KB
    float* zsqg = (float*)(ws + off);                    off += 8192ull * 4;     // 32 KB

    k_nsgt<<<256, 512, 0, stream>>>(Z, pa, qmu, qsqrt, Wbf, Hbuf, Zpan, zsqg);
    k_main<<<512, 512, 0, stream>>>(X, Zpan, zsqg, pa, Hbuf, Wbf, out);
}

// Round 22
// 59.966 us; speedup vs baseline: 1.1939x; 1.1939x over previous
//
#include <hip/hip_runtime.h>
#include <hip/hip_bf16.h>

// Problem constants
#define NN      2048
#define NODES   64
#define DIN     4
#define DOUT    4
#define MM      128
#define DEG     8
#define PP      32
#define JITTER  1e-4f

typedef __attribute__((ext_vector_type(8))) short short8;
typedef __attribute__((ext_vector_type(4))) float f32x4;
typedef __attribute__((ext_vector_type(4))) unsigned short bf16x4;

// Hbuf per-node layout (4 tiles of 16384 bf16): M0 M1 M2 M3
#define HSTRIDE 65536

__device__ __forceinline__ unsigned short f2b(float f) {
    union { float f; unsigned int u; } v; v.f = f;
    unsigned int u = v.u;
    u += 0x7fffu + ((u >> 16) & 1u);
    return (unsigned short)(u >> 16);
}
__device__ __forceinline__ float b2f(unsigned short h) {
    union { unsigned int u; float f; } v; v.u = ((unsigned int)h) << 16;
    return v.f;
}
// pack 2x f32x4 -> short8 (bf16 rne), accumulating sum of squares of ROUNDED vals
__device__ __forceinline__ short8 pack8(f32x4 a, f32x4 b, float& sq) {
    short8 r;
    #pragma unroll
    for (int e = 0; e < 4; e++) {
        unsigned short ha = f2b(a[e]), hb = f2b(b[e]);
        float fa = b2f(ha), fb = b2f(hb);
        sq += fa * fa + fb * fb;
        r[e] = (short)ha; r[e + 4] = (short)hb;
    }
    return r;
}

// async global->LDS, 16B per lane. LDS dest = wave-uniform base + lane*16.
__device__ __forceinline__ void gload16(const unsigned short* g, unsigned short* l) {
    __builtin_amdgcn_global_load_lds(
        (const __attribute__((address_space(1))) unsigned int*)g,
        (__attribute__((address_space(3))) unsigned int*)l, 16, 0, 0);
}

// ---------------- K1: fused NS + W + M_d (one block per (node,d)) -----------
// Identical to R21 (validated): Kinv in LDS; M_d = G^T G - Kinv -> Hbuf.
__global__ __launch_bounds__(512) void k_nsgt(const float* __restrict__ Z,
                                              const int* __restrict__ pa,
                                              const float* __restrict__ qmu,
                                              const float* __restrict__ qsqrt,
                                              unsigned short* __restrict__ Wbf,
                                              unsigned short* __restrict__ Hbuf,
                                              unsigned short* __restrict__ Zpan,
                                              float* __restrict__ zsqg) {
    __shared__ unsigned short SA[16384];  // D -> Kinv (bf16, swizzled)
    __shared__ unsigned short SB[16384];  // S -> qmuT -> Lq -> GT
    __shared__ float zsqs[128];
    __shared__ int cols[32];
    int bid = blockIdx.x, t = threadIdx.x;
    int node = (bid & 7) + 8 * (bid >> 5);   // node's 4 d-blocks on one XCD
    int d = (bid >> 3) & 3;
    int wv = t >> 6, ln = t & 63;
    if (t < 32) cols[t] = pa[node * 32 + t];
    __syncthreads();

    int wmI = wv & 1, wnI = wv >> 1;      // 2 x 4 wave grid
    int wm = wmI * 64, wn = wnI * 32;
    int lr = ln & 15, lk = ln >> 4;
    int cg0 = cols[lk * 8], cg1 = cols[lk * 8 + 4];

    short8 zv[4], xv[2];
    #pragma unroll
    for (int mi = 0; mi < 4; mi++) {
        int m = wm + mi * 16 + lr;
        float sq = 0.f;
        zv[mi] = pack8(*(const f32x4*)(Z + (size_t)m * 256 + cg0),
                       *(const f32x4*)(Z + (size_t)m * 256 + cg1), sq);
        sq += __shfl_xor(sq, 16);
        sq += __shfl_xor(sq, 32);
        if (lk == 0) zsqs[m] = sq;
        if (d == 0 && wnI == 0)
            *(short8*)(Zpan + (size_t)node * 4096 + (size_t)m * 32 + lk * 8) = zv[mi];
    }
    #pragma unroll
    for (int ni = 0; ni < 2; ni++) {
        int x = wn + ni * 16 + lr;
        float sq = 0.f;
        xv[ni] = pack8(*(const f32x4*)(Z + (size_t)x * 256 + cg0),
                       *(const f32x4*)(Z + (size_t)x * 256 + cg1), sq);
    }
    __syncthreads();
    if (d == 0 && t < 128) zsqg[node * 128 + t] = zsqs[t];

    f32x4 dacc[4][2] = {};
    #pragma unroll
    for (int mi = 0; mi < 4; mi++)
        #pragma unroll
        for (int ni = 0; ni < 2; ni++)
            dacc[mi][ni] = __builtin_amdgcn_mfma_f32_16x16x32_bf16(zv[mi], xv[ni], dacc[mi][ni], 0, 0, 0);

    #pragma unroll
    for (int mi = 0; mi < 4; mi++) {
        int mb = wm + mi * 16 + lk * 4;
        f32x4 zs4 = *(const f32x4*)(zsqs + mb);
        #pragma unroll
        for (int ni = 0; ni < 2; ni++) {
            int x = wn + ni * 16 + lr;
            float xs = zsqs[x];
            bf16x4 kv4;
            #pragma unroll
            for (int j = 0; j < 4; j++) {
                float sq = fmaxf(zs4[j] + xs - 2.0f * dacc[mi][ni][j], 0.0f);
                float v = (mb + j == x) ? JITTER : __expf(-0.5f * sq);
                kv4[j] = f2b(v);
            }
            *(bf16x4*)(SA + x * 128 + (((mb >> 3) ^ (x & 7)) * 8) + (mb & 7)) = kv4;
        }
    }
    __syncthreads();

    // GEMM1: S = D @ D^T
    f32x4 acc1[4][2] = {};
    #pragma unroll
    for (int ks = 0; ks < 4; ks++) {
        int seg = ks * 4 + lk;
        short8 av[4], bv[2];
        #pragma unroll
        for (int mi = 0; mi < 4; mi++) {
            int r = wm + mi * 16 + lr;
            av[mi] = *(const short8*)(SA + r * 128 + ((seg ^ (r & 7)) * 8));
        }
        #pragma unroll
        for (int ni = 0; ni < 2; ni++) {
            int x = wn + ni * 16 + lr;
            bv[ni] = *(const short8*)(SA + x * 128 + ((seg ^ (x & 7)) * 8));
        }
        #pragma unroll
        for (int mi = 0; mi < 4; mi++)
            #pragma unroll
            for (int ni = 0; ni < 2; ni++)
                acc1[mi][ni] = __builtin_amdgcn_mfma_f32_16x16x32_bf16(av[mi], bv[ni], acc1[mi][ni], 0, 0, 0);
    }
    #pragma unroll
    for (int mi = 0; mi < 4; mi++)
        #pragma unroll
        for (int ni = 0; ni < 2; ni++)
            #pragma unroll
            for (int j = 0; j < 4; j++) {
                int rr = wm + mi * 16 + lk * 4 + j;
                int cc = wn + ni * 16 + lr;
                SB[rr * 128 + (((cc >> 3) ^ (rr & 7)) * 8) + (cc & 7)] = f2b(acc1[mi][ni][j]);
            }
    __syncthreads();

    // GEMM2: DS = D @ S^T
    f32x4 acc2[4][2] = {};
    #pragma unroll
    for (int ks = 0; ks < 4; ks++) {
        int seg = ks * 4 + lk;
        short8 av[4], bv[2];
        #pragma unroll
        for (int mi = 0; mi < 4; mi++) {
            int r = wm + mi * 16 + lr;
            av[mi] = *(const short8*)(SA + r * 128 + ((seg ^ (r & 7)) * 8));
        }
        #pragma unroll
        for (int ni = 0; ni < 2; ni++) {
            int x = wn + ni * 16 + lr;
            bv[ni] = *(const short8*)(SB + x * 128 + ((seg ^ (x & 7)) * 8));
        }
        #pragma unroll
        for (int mi = 0; mi < 4; mi++)
            #pragma unroll
            for (int ni = 0; ni < 2; ni++)
                acc2[mi][ni] = __builtin_amdgcn_mfma_f32_16x16x32_bf16(av[mi], bv[ni], acc2[mi][ni], 0, 0, 0);
    }
    __syncthreads();

    // Kinv = I - D + S - DS -> SA (in place, stays in LDS)
    #pragma unroll
    for (int mi = 0; mi < 4; mi++)
        #pragma unroll
        for (int ni = 0; ni < 2; ni++)
            #pragma unroll
            for (int j = 0; j < 4; j++) {
                int rr = wm + mi * 16 + lk * 4 + j;
                int cc = wn + ni * 16 + lr;
                int sw = rr * 128 + (((cc >> 3) ^ (rr & 7)) * 8) + (cc & 7);
                float dv = b2f(SA[sw]);
                float eye = (rr == cc) ? 1.0f : 0.0f;
                float kinv = eye - dv + acc1[mi][ni][j] - acc2[mi][ni][j];
                SA[sw] = f2b(kinv);
            }
    if (d == 0) {
        for (int q = t; q < 2048; q += 512) {
            int dd = q >> 7, mm = q & 127;
            unsigned short val = 0;
            if (dd < 4) val = f2b(qmu[mm * 256 + node * 4 + dd]);
            SB[dd * 128 + (((mm >> 3) ^ (dd & 7)) * 8) + (mm & 7)] = val;
        }
    }
    __syncthreads();

    if (d == 0) {
        // W^T = qmuT @ Kinv (16 x 128); wave wv owns cols wv*16..+15
        f32x4 wacc = {};
        #pragma unroll
        for (int ks = 0; ks < 4; ks++) {
            int seg = ks * 4 + lk;
            short8 aq = *(const short8*)(SB + lr * 128 + ((seg ^ (lr & 7)) * 8));
            int x = wv * 16 + lr;
            short8 bk = *(const short8*)(SA + x * 128 + ((seg ^ (x & 7)) * 8));
            wacc = __builtin_amdgcn_mfma_f32_16x16x32_bf16(aq, bk, wacc, 0, 0, 0);
        }
        unsigned short* Wg = Wbf + (size_t)node * 2048;
        #pragma unroll
        for (int j = 0; j < 4; j++) {
            int dd = lk * 4 + j;
            int mm = wv * 16 + lr;
            Wg[dd * 128 + (((mm >> 3) ^ (dd & 7)) * 8) + (mm & 7)] = f2b(wacc[j]);
        }
    }
    __syncthreads();   // W's SB reads done before Lq overwrites SB

    // stage Lq_d tril (fp32 -> bf16, transposed+masked, swizzled) into SB
    {
        const float* Lq = qsqrt + (size_t)(node * 4 + d) * 16384;
        int m = t & 127, ph = t >> 7;
        for (int pp = 0; pp < 32; pp++) {
            int p = ph * 32 + pp;
            float v = 0.f;
            if (p >= m) v = Lq[p * 128 + m];
            SB[m * 128 + (((p >> 3) ^ (m & 7)) * 8) + (p & 7)] = f2b(v);
        }
    }
    __syncthreads();

    // G_d = Lq_d^T @ Kinv  (A = SB (Lq^T), B = SA (Kinv, symmetric))
    f32x4 gacc[4][2] = {};
    #pragma unroll
    for (int ks = 0; ks < 4; ks++) {
        int seg = ks * 4 + lk;
        short8 av[4], bv[2];
        #pragma unroll
        for (int mi = 0; mi < 4; mi++) {
            int r = wm + mi * 16 + lr;
            av[mi] = *(const short8*)(SB + r * 128 + ((seg ^ (r & 7)) * 8));
        }
        #pragma unroll
        for (int ni = 0; ni < 2; ni++) {
            int x = wn + ni * 16 + lr;
            bv[ni] = *(const short8*)(SA + x * 128 + ((seg ^ (x & 7)) * 8));
        }
        #pragma unroll
        for (int mi = 0; mi < 4; mi++)
            #pragma unroll
            for (int ni = 0; ni < 2; ni++)
                gacc[mi][ni] = __builtin_amdgcn_mfma_f32_16x16x32_bf16(av[mi], bv[ni], gacc[mi][ni], 0, 0, 0);
    }
    __syncthreads();   // all Lq reads of SB done before GT overwrites it

    // store G TRANSPOSED into SB: GT[i=G-col][m=G-row], swizzled
    #pragma unroll
    for (int mi = 0; mi < 4; mi++)
        #pragma unroll
        for (int ni = 0; ni < 2; ni++)
            #pragma unroll
            for (int j = 0; j < 4; j++) {
                int rr = wm + mi * 16 + lk * 4 + j;   // G row (m)
                int cc = wn + ni * 16 + lr;           // G col (i)
                SB[cc * 128 + (((rr >> 3) ^ (cc & 7)) * 8) + (rr & 7)] = f2b(gacc[mi][ni][j]);
            }
    __syncthreads();

    // M_d = GT @ GT^T - Kinv  (= G^T G - Kinv, symmetric) -> Hbuf tile d
    f32x4 macc[4][2] = {};
    #pragma unroll
    for (int ks = 0; ks < 4; ks++) {
        int seg = ks * 4 + lk;
        short8 av[4], bv[2];
        #pragma unroll
        for (int mi = 0; mi < 4; mi++) {
            int r = wm + mi * 16 + lr;
            av[mi] = *(const short8*)(SB + r * 128 + ((seg ^ (r & 7)) * 8));
        }
        #pragma unroll
        for (int ni = 0; ni < 2; ni++) {
            int x = wn + ni * 16 + lr;
            bv[ni] = *(const short8*)(SB + x * 128 + ((seg ^ (x & 7)) * 8));
        }
        #pragma unroll
        for (int mi = 0; mi < 4; mi++)
            #pragma unroll
            for (int ni = 0; ni < 2; ni++)
                macc[mi][ni] = __builtin_amdgcn_mfma_f32_16x16x32_bf16(av[mi], bv[ni], macc[mi][ni], 0, 0, 0);
    }
    unsigned short* Mg = Hbuf + (size_t)node * HSTRIDE + (size_t)d * 16384;
    #pragma unroll
    for (int mi = 0; mi < 4; mi++)
        #pragma unroll
        for (int ni = 0; ni < 2; ni++)
            #pragma unroll
            for (int j = 0; j < 4; j++) {
                int rr = wm + mi * 16 + lk * 4 + j;
                int cc = wn + ni * 16 + lr;
                int sw = rr * 128 + (((cc >> 3) ^ (rr & 7)) * 8) + (cc & 7);
                float mval = macc[mi][ni][j] - b2f(SA[sw]);
                Mg[sw] = f2b(mval);
            }
}

// ---------------- K2: k_main, 4 M-tiles; k split LDS-strip/registers --------
// 512 blocks x 512 threads, 2 blocks/CU (LDS 64 KB). Single tile buffer A0
// (stage/compute barrier-separated; co-resident block covers the stalls).
// it=0's k persists in KS strips (read back b64 in the epilogue);
// it=1's k lives in kreg1[8] (16 VGPR). Phase-2 live regs ~95 -> no spill.
__global__ __launch_bounds__(512, 1) void k_main(const float* __restrict__ X,
                                                 const unsigned short* __restrict__ Zpan,
                                                 const float* __restrict__ zsqg,
                                                 const int* __restrict__ pa,
                                                 const unsigned short* __restrict__ Hbuf,
                                                 const unsigned short* __restrict__ Wbf,
                                                 float* __restrict__ out) {
    __shared__ unsigned short A0[16384];   // it1 transient strips, then M tiles
    __shared__ unsigned short KS[16384];   // it0 strips (persist through phase 2)

    int bid = blockIdx.x;
    int node = (bid & 7) + 8 * (bid >> 6);   // node's 8 blocks on one XCD
    int half = (bid >> 3) & 7;
    int x0 = half * 256;
    int t = threadIdx.x;
    int wv = t >> 6, ln = t & 63;
    int lr = ln & 15, lk = ln >> 4;

    const unsigned short* Asrc = Hbuf + (size_t)node * HSTRIDE;
    const unsigned short* Wsrc = Wbf + (size_t)node * 2048;
    int cg0 = pa[node * 32 + lk * 8];
    int cg1 = pa[node * 32 + lk * 8 + 4];

    unsigned short* strip0 = KS + wv * 2048;   // it=0, persistent
    unsigned short* strip1 = A0 + wv * 2048;   // it=1, transient (pre-staging)

    // Z fragments: coalesced b128 from the precomputed panel (L2-hot)
    const unsigned short* Zp = Zpan + (size_t)node * 4096;
    short8 zv[8];
    #pragma unroll
    for (int mi = 0; mi < 8; mi++)
        zv[mi] = *(const short8*)(Zp + (size_t)(mi * 16 + lr) * 32 + lk * 8);
    // W fragments once (global, pre-swizzled)
    short8 aw[4];
    #pragma unroll
    for (int ks = 0; ks < 4; ks++)
        aw[ks] = *(const short8*)(Wsrc + lr * 128 + (((ks * 4 + lk) ^ (lr & 7)) * 8));

    // ---- phase 1: 2 col-groups -> bvAll + (strip0 | kreg1) + mean ----
    const float* Xb = X + (size_t)(x0 + wv * 32 + lr) * 256;
    const float* zsq_n = zsqg + node * 128;
    f32x4 xr0 = *(const f32x4*)(Xb + cg0);
    f32x4 xr1 = *(const f32x4*)(Xb + cg1);
    short8 bvAll[2][4];
    bf16x4 kreg1[8];
    f32x4 maccA[2];
    #pragma unroll
    for (int it = 0; it < 2; it++) {
        unsigned short* strip = it ? strip1 : strip0;
        float xs = 0.f;
        short8 xv = pack8(xr0, xr1, xs);
        xs += __shfl_xor(xs, 16);
        xs += __shfl_xor(xs, 32);
        if (it < 1) {   // next col-group = +16 rows of X
            xr0 = *(const f32x4*)(Xb + 4096 + cg0);
            xr1 = *(const f32x4*)(Xb + 4096 + cg1);
        }
        f32x4 dacc[8] = {};
        #pragma unroll
        for (int mi = 0; mi < 8; mi++)
            dacc[mi] = __builtin_amdgcn_mfma_f32_16x16x32_bf16(zv[mi], xv, dacc[mi], 0, 0, 0);
        #pragma unroll
        for (int mi = 0; mi < 8; mi++) {
            int mb = mi * 16 + lk * 4;
            f32x4 zs4 = *(const f32x4*)(zsq_n + mb);
            bf16x4 kv4;
            #pragma unroll
            for (int j = 0; j < 4; j++) {
                float sq = fmaxf(zs4[j] + xs - 2.0f * dacc[mi][j], 0.0f);
                kv4[j] = f2b(__expf(-0.5f * sq));
            }
            if (it) kreg1[mi] = kv4;
            *(bf16x4*)(strip + lr * 128 + (((mb >> 3) ^ (lr & 7)) * 8) + (mb & 7)) = kv4;
        }
        #pragma unroll
        for (int ks = 0; ks < 4; ks++)
            bvAll[it][ks] = *(const short8*)(strip + lr * 128 + (((ks * 4 + lk) ^ (lr & 7)) * 8));
        f32x4 m4 = {};
        #pragma unroll
        for (int ks = 0; ks < 4; ks++)
            m4 = __builtin_amdgcn_mfma_f32_16x16x32_bf16(aw[ks], bvAll[it][ks], m4, 0, 0, 0);
        maccA[it] = m4;
    }
    __syncthreads();   // strip1 reads done; A0 free for tile staging

    // issue tile0 -> A0
    #pragma unroll
    for (int i = 0; i < 4; i++) {
        int ch = i * 8 + wv;
        gload16(Asrc + ch * 512 + ln * 8, A0 + ch * 512);
    }

    // ---- phase 2: 4 M-tiles, single buffer; dot-with-k epilogue ----
    float vout[4][2];
    #pragma unroll
    for (int tt = 0; tt < 4; tt++) {
        __syncthreads();   // tile tt landed (vmcnt drained at barrier)
        float ssum[2] = {0.f, 0.f};
        __builtin_amdgcn_s_setprio(1);
        #pragma unroll
        for (int mi = 0; mi < 8; mi++) {
            int r = mi * 16 + lr;
            int mb = mi * 16 + lk * 4;
            f32x4 a4[2] = {};
            #pragma unroll
            for (int ks = 0; ks < 4; ks++) {
                short8 av = *(const short8*)(A0 + r * 128 + (((ks * 4 + lk) ^ (r & 7)) * 8));
                #pragma unroll
                for (int it = 0; it < 2; it++)
                    a4[it] = __builtin_amdgcn_mfma_f32_16x16x32_bf16(av, bvAll[it][ks], a4[it], 0, 0, 0);
            }
            bf16x4 k0 = *(const bf16x4*)(strip0 + lr * 128 + (((mb >> 3) ^ (lr & 7)) * 8) + (mb & 7));
            #pragma unroll
            for (int j = 0; j < 4; j++) {
                ssum[0] += a4[0][j] * b2f(k0[j]);
                ssum[1] += a4[1][j] * b2f(kreg1[mi][j]);
            }
        }
        __builtin_amdgcn_s_setprio(0);
        __syncthreads();   // all A0 reads done before restaging
        if (tt < 3) {
            const unsigned short* ns = Asrc + (size_t)(tt + 1) * 16384;
            #pragma unroll
            for (int i = 0; i < 4; i++) {
                int ch = i * 8 + wv;
                gload16(ns + ch * 512 + ln * 8, A0 + ch * 512);
            }
        }
        #pragma unroll
        for (int it = 0; it < 2; it++) {
            float sv = ssum[it];
            sv += __shfl_xor(sv, 16);
            sv += __shfl_xor(sv, 32);
            vout[tt][it] = sv;
        }
    }

    // ---- output ----
    if (lk == 0) {
        #pragma unroll
        for (int it = 0; it < 2; it++) {
            int x = x0 + wv * 32 + it * 16 + lr;
            f32x4 mv, vv;
            #pragma unroll
            for (int j = 0; j < 4; j++) {
                mv[j] = maccA[it][j];
                vv[j] = 1.0f + vout[j][it];
            }
            *(f32x4*)(out + (size_t)x * 256 + node * 4) = mv;
            *(f32x4*)(out + 524288 + (size_t)x * 256 + node * 4) = vv;
        }
    }
}

extern "C" void kernel_launch(void* const* d_in, const int* in_sizes, int n_in,
                              void* d_out, int out_size, void* d_ws, size_t ws_size,
                              hipStream_t stream) {
    const float* X = (const float*)d_in[0];
    const float* Z = (const float*)d_in[1];
    const float* qmu = (const float*)d_in[2];
    const float* qsqrt = (const float*)d_in[3];
    const int* pa = (const int*)d_in[4];
    float* out = (float*)d_out;

    char* ws = (char*)d_ws;
    size_t off = 0;
    unsigned short* Wbf = (unsigned short*)(ws + off);   off += 131072ull * 2;   // 256 KB
    unsigned short* Hbuf = (unsigned short*)(ws + off);  off += 4194304ull * 2;  // 8 MB
    unsigned short* Zpan = (unsigned short*)(ws + off);  off += 262144ull * 2;   // 512 KB
    float* zsqg = (float*)(ws + off);                    off += 8192ull * 4;     // 32 KB

    k_nsgt<<<256, 512, 0, stream>>>(Z, pa, qmu, qsqrt, Wbf, Hbuf, Zpan, zsqg);
    k_main<<<512, 512, 0, stream>>>(X, Zpan, zsqg, pa, Hbuf, Wbf, out);
}

// Round 23
// 57.128 us; speedup vs baseline: 1.2532x; 1.0497x over previous
//
#include <hip/hip_runtime.h>
#include <hip/hip_bf16.h>

// Problem constants
#define NN      2048
#define NODES   64
#define DIN     4
#define DOUT    4
#define MM      128
#define DEG     8
#define PP      32
#define JITTER  1e-4f

typedef __attribute__((ext_vector_type(8))) short short8;
typedef __attribute__((ext_vector_type(4))) float f32x4;
typedef __attribute__((ext_vector_type(4))) unsigned short bf16x4;

// Hbuf per-node layout (4 tiles of 16384 bf16): M0 M1 M2 M3
#define HSTRIDE 65536

__device__ __forceinline__ unsigned short f2b(float f) {
    union { float f; unsigned int u; } v; v.f = f;
    unsigned int u = v.u;
    u += 0x7fffu + ((u >> 16) & 1u);
    return (unsigned short)(u >> 16);
}
__device__ __forceinline__ float b2f(unsigned short h) {
    union { unsigned int u; float f; } v; v.u = ((unsigned int)h) << 16;
    return v.f;
}
// pack 2x f32x4 -> short8 (bf16 rne), accumulating sum of squares of ROUNDED vals
__device__ __forceinline__ short8 pack8(f32x4 a, f32x4 b, float& sq) {
    short8 r;
    #pragma unroll
    for (int e = 0; e < 4; e++) {
        unsigned short ha = f2b(a[e]), hb = f2b(b[e]);
        float fa = b2f(ha), fb = b2f(hb);
        sq += fa * fa + fb * fb;
        r[e] = (short)ha; r[e + 4] = (short)hb;
    }
    return r;
}

// async global->LDS, 16B per lane. LDS dest = wave-uniform base + lane*16.
__device__ __forceinline__ void gload16(const unsigned short* g, unsigned short* l) {
    __builtin_amdgcn_global_load_lds(
        (const __attribute__((address_space(1))) unsigned int*)g,
        (__attribute__((address_space(3))) unsigned int*)l, 16, 0, 0);
}

// ---------------- K1: fused NS + W + M_d (one block per (node,d)) -----------
// Identical to R21/R22 (validated): Kinv in LDS; M_d = G^T G - Kinv -> Hbuf.
__global__ __launch_bounds__(512) void k_nsgt(const float* __restrict__ Z,
                                              const int* __restrict__ pa,
                                              const float* __restrict__ qmu,
                                              const float* __restrict__ qsqrt,
                                              unsigned short* __restrict__ Wbf,
                                              unsigned short* __restrict__ Hbuf,
                                              unsigned short* __restrict__ Zpan,
                                              float* __restrict__ zsqg) {
    __shared__ unsigned short SA[16384];  // D -> Kinv (bf16, swizzled)
    __shared__ unsigned short SB[16384];  // S -> qmuT -> Lq -> GT
    __shared__ float zsqs[128];
    __shared__ int cols[32];
    int bid = blockIdx.x, t = threadIdx.x;
    int node = (bid & 7) + 8 * (bid >> 5);   // node's 4 d-blocks on one XCD
    int d = (bid >> 3) & 3;
    int wv = t >> 6, ln = t & 63;
    if (t < 32) cols[t] = pa[node * 32 + t];
    __syncthreads();

    int wmI = wv & 1, wnI = wv >> 1;      // 2 x 4 wave grid
    int wm = wmI * 64, wn = wnI * 32;
    int lr = ln & 15, lk = ln >> 4;
    int cg0 = cols[lk * 8], cg1 = cols[lk * 8 + 4];

    short8 zv[4], xv[2];
    #pragma unroll
    for (int mi = 0; mi < 4; mi++) {
        int m = wm + mi * 16 + lr;
        float sq = 0.f;
        zv[mi] = pack8(*(const f32x4*)(Z + (size_t)m * 256 + cg0),
                       *(const f32x4*)(Z + (size_t)m * 256 + cg1), sq);
        sq += __shfl_xor(sq, 16);
        sq += __shfl_xor(sq, 32);
        if (lk == 0) zsqs[m] = sq;
        if (d == 0 && wnI == 0)
            *(short8*)(Zpan + (size_t)node * 4096 + (size_t)m * 32 + lk * 8) = zv[mi];
    }
    #pragma unroll
    for (int ni = 0; ni < 2; ni++) {
        int x = wn + ni * 16 + lr;
        float sq = 0.f;
        xv[ni] = pack8(*(const f32x4*)(Z + (size_t)x * 256 + cg0),
                       *(const f32x4*)(Z + (size_t)x * 256 + cg1), sq);
    }
    __syncthreads();
    if (d == 0 && t < 128) zsqg[node * 128 + t] = zsqs[t];

    f32x4 dacc[4][2] = {};
    #pragma unroll
    for (int mi = 0; mi < 4; mi++)
        #pragma unroll
        for (int ni = 0; ni < 2; ni++)
            dacc[mi][ni] = __builtin_amdgcn_mfma_f32_16x16x32_bf16(zv[mi], xv[ni], dacc[mi][ni], 0, 0, 0);

    #pragma unroll
    for (int mi = 0; mi < 4; mi++) {
        int mb = wm + mi * 16 + lk * 4;
        f32x4 zs4 = *(const f32x4*)(zsqs + mb);
        #pragma unroll
        for (int ni = 0; ni < 2; ni++) {
            int x = wn + ni * 16 + lr;
            float xs = zsqs[x];
            bf16x4 kv4;
            #pragma unroll
            for (int j = 0; j < 4; j++) {
                float sq = fmaxf(zs4[j] + xs - 2.0f * dacc[mi][ni][j], 0.0f);
                float v = (mb + j == x) ? JITTER : __expf(-0.5f * sq);
                kv4[j] = f2b(v);
            }
            *(bf16x4*)(SA + x * 128 + (((mb >> 3) ^ (x & 7)) * 8) + (mb & 7)) = kv4;
        }
    }
    __syncthreads();

    // GEMM1: S = D @ D^T
    f32x4 acc1[4][2] = {};
    #pragma unroll
    for (int ks = 0; ks < 4; ks++) {
        int seg = ks * 4 + lk;
        short8 av[4], bv[2];
        #pragma unroll
        for (int mi = 0; mi < 4; mi++) {
            int r = wm + mi * 16 + lr;
            av[mi] = *(const short8*)(SA + r * 128 + ((seg ^ (r & 7)) * 8));
        }
        #pragma unroll
        for (int ni = 0; ni < 2; ni++) {
            int x = wn + ni * 16 + lr;
            bv[ni] = *(const short8*)(SA + x * 128 + ((seg ^ (x & 7)) * 8));
        }
        #pragma unroll
        for (int mi = 0; mi < 4; mi++)
            #pragma unroll
            for (int ni = 0; ni < 2; ni++)
                acc1[mi][ni] = __builtin_amdgcn_mfma_f32_16x16x32_bf16(av[mi], bv[ni], acc1[mi][ni], 0, 0, 0);
    }
    #pragma unroll
    for (int mi = 0; mi < 4; mi++)
        #pragma unroll
        for (int ni = 0; ni < 2; ni++)
            #pragma unroll
            for (int j = 0; j < 4; j++) {
                int rr = wm + mi * 16 + lk * 4 + j;
                int cc = wn + ni * 16 + lr;
                SB[rr * 128 + (((cc >> 3) ^ (rr & 7)) * 8) + (cc & 7)] = f2b(acc1[mi][ni][j]);
            }
    __syncthreads();

    // GEMM2: DS = D @ S^T
    f32x4 acc2[4][2] = {};
    #pragma unroll
    for (int ks = 0; ks < 4; ks++) {
        int seg = ks * 4 + lk;
        short8 av[4], bv[2];
        #pragma unroll
        for (int mi = 0; mi < 4; mi++) {
            int r = wm + mi * 16 + lr;
            av[mi] = *(const short8*)(SA + r * 128 + ((seg ^ (r & 7)) * 8));
        }
        #pragma unroll
        for (int ni = 0; ni < 2; ni++) {
            int x = wn + ni * 16 + lr;
            bv[ni] = *(const short8*)(SB + x * 128 + ((seg ^ (x & 7)) * 8));
        }
        #pragma unroll
        for (int mi = 0; mi < 4; mi++)
            #pragma unroll
            for (int ni = 0; ni < 2; ni++)
                acc2[mi][ni] = __builtin_amdgcn_mfma_f32_16x16x32_bf16(av[mi], bv[ni], acc2[mi][ni], 0, 0, 0);
    }
    __syncthreads();

    // Kinv = I - D + S - DS -> SA (in place, stays in LDS)
    #pragma unroll
    for (int mi = 0; mi < 4; mi++)
        #pragma unroll
        for (int ni = 0; ni < 2; ni++)
            #pragma unroll
            for (int j = 0; j < 4; j++) {
                int rr = wm + mi * 16 + lk * 4 + j;
                int cc = wn + ni * 16 + lr;
                int sw = rr * 128 + (((cc >> 3) ^ (rr & 7)) * 8) + (cc & 7);
                float dv = b2f(SA[sw]);
                float eye = (rr == cc) ? 1.0f : 0.0f;
                float kinv = eye - dv + acc1[mi][ni][j] - acc2[mi][ni][j];
                SA[sw] = f2b(kinv);
            }
    if (d == 0) {
        for (int q = t; q < 2048; q += 512) {
            int dd = q >> 7, mm = q & 127;
            unsigned short val = 0;
            if (dd < 4) val = f2b(qmu[mm * 256 + node * 4 + dd]);
            SB[dd * 128 + (((mm >> 3) ^ (dd & 7)) * 8) + (mm & 7)] = val;
        }
    }
    __syncthreads();

    if (d == 0) {
        // W^T = qmuT @ Kinv (16 x 128); wave wv owns cols wv*16..+15
        f32x4 wacc = {};
        #pragma unroll
        for (int ks = 0; ks < 4; ks++) {
            int seg = ks * 4 + lk;
            short8 aq = *(const short8*)(SB + lr * 128 + ((seg ^ (lr & 7)) * 8));
            int x = wv * 16 + lr;
            short8 bk = *(const short8*)(SA + x * 128 + ((seg ^ (x & 7)) * 8));
            wacc = __builtin_amdgcn_mfma_f32_16x16x32_bf16(aq, bk, wacc, 0, 0, 0);
        }
        unsigned short* Wg = Wbf + (size_t)node * 2048;
        #pragma unroll
        for (int j = 0; j < 4; j++) {
            int dd = lk * 4 + j;
            int mm = wv * 16 + lr;
            Wg[dd * 128 + (((mm >> 3) ^ (dd & 7)) * 8) + (mm & 7)] = f2b(wacc[j]);
        }
    }
    __syncthreads();   // W's SB reads done before Lq overwrites SB

    // stage Lq_d tril (fp32 -> bf16, transposed+masked, swizzled) into SB
    {
        const float* Lq = qsqrt + (size_t)(node * 4 + d) * 16384;
        int m = t & 127, ph = t >> 7;
        for (int pp = 0; pp < 32; pp++) {
            int p = ph * 32 + pp;
            float v = 0.f;
            if (p >= m) v = Lq[p * 128 + m];
            SB[m * 128 + (((p >> 3) ^ (m & 7)) * 8) + (p & 7)] = f2b(v);
        }
    }
    __syncthreads();

    // G_d = Lq_d^T @ Kinv  (A = SB (Lq^T), B = SA (Kinv, symmetric))
    f32x4 gacc[4][2] = {};
    #pragma unroll
    for (int ks = 0; ks < 4; ks++) {
        int seg = ks * 4 + lk;
        short8 av[4], bv[2];
        #pragma unroll
        for (int mi = 0; mi < 4; mi++) {
            int r = wm + mi * 16 + lr;
            av[mi] = *(const short8*)(SB + r * 128 + ((seg ^ (r & 7)) * 8));
        }
        #pragma unroll
        for (int ni = 0; ni < 2; ni++) {
            int x = wn + ni * 16 + lr;
            bv[ni] = *(const short8*)(SA + x * 128 + ((seg ^ (x & 7)) * 8));
        }
        #pragma unroll
        for (int mi = 0; mi < 4; mi++)
            #pragma unroll
            for (int ni = 0; ni < 2; ni++)
                gacc[mi][ni] = __builtin_amdgcn_mfma_f32_16x16x32_bf16(av[mi], bv[ni], gacc[mi][ni], 0, 0, 0);
    }
    __syncthreads();   // all Lq reads of SB done before GT overwrites it

    // store G TRANSPOSED into SB: GT[i=G-col][m=G-row], swizzled
    #pragma unroll
    for (int mi = 0; mi < 4; mi++)
        #pragma unroll
        for (int ni = 0; ni < 2; ni++)
            #pragma unroll
            for (int j = 0; j < 4; j++) {
                int rr = wm + mi * 16 + lk * 4 + j;   // G row (m)
                int cc = wn + ni * 16 + lr;           // G col (i)
                SB[cc * 128 + (((rr >> 3) ^ (cc & 7)) * 8) + (rr & 7)] = f2b(gacc[mi][ni][j]);
            }
    __syncthreads();

    // M_d = GT @ GT^T - Kinv  (= G^T G - Kinv, symmetric) -> Hbuf tile d
    f32x4 macc[4][2] = {};
    #pragma unroll
    for (int ks = 0; ks < 4; ks++) {
        int seg = ks * 4 + lk;
        short8 av[4], bv[2];
        #pragma unroll
        for (int mi = 0; mi < 4; mi++) {
            int r = wm + mi * 16 + lr;
            av[mi] = *(const short8*)(SB + r * 128 + ((seg ^ (r & 7)) * 8));
        }
        #pragma unroll
        for (int ni = 0; ni < 2; ni++) {
            int x = wn + ni * 16 + lr;
            bv[ni] = *(const short8*)(SB + x * 128 + ((seg ^ (x & 7)) * 8));
        }
        #pragma unroll
        for (int mi = 0; mi < 4; mi++)
            #pragma unroll
            for (int ni = 0; ni < 2; ni++)
                macc[mi][ni] = __builtin_amdgcn_mfma_f32_16x16x32_bf16(av[mi], bv[ni], macc[mi][ni], 0, 0, 0);
    }
    unsigned short* Mg = Hbuf + (size_t)node * HSTRIDE + (size_t)d * 16384;
    #pragma unroll
    for (int mi = 0; mi < 4; mi++)
        #pragma unroll
        for (int ni = 0; ni < 2; ni++)
            #pragma unroll
            for (int j = 0; j < 4; j++) {
                int rr = wm + mi * 16 + lk * 4 + j;
                int cc = wn + ni * 16 + lr;
                int sw = rr * 128 + (((cc >> 3) ^ (rr & 7)) * 8) + (cc & 7);
                float mval = macc[mi][ni][j] - b2f(SA[sw]);
                Mg[sw] = f2b(mval);
            }
}

// ---------------- K2: k_main, 4 M-tiles; double-buffered; k split -----------
// 512 blocks x 512 threads, LDS = A0+A1+KS = 48 KB -> 2 blocks/CU.
// R20's one-barrier-per-tile double-buffered pipeline on R22's 4-tile M-form:
// it=0's k persists in KS strips (b64 readback in epilogue); it=1's k in
// kreg1[8] (16 VGPR); strip1 transiently in A1 before staging starts.
__global__ __launch_bounds__(512, 1) void k_main(const float* __restrict__ X,
                                                 const unsigned short* __restrict__ Zpan,
                                                 const float* __restrict__ zsqg,
                                                 const int* __restrict__ pa,
                                                 const unsigned short* __restrict__ Hbuf,
                                                 const unsigned short* __restrict__ Wbf,
                                                 float* __restrict__ out) {
    __shared__ unsigned short A0[16384];   // tiles 0,2
    __shared__ unsigned short A1[16384];   // it1 strips, then tiles 1,3
    __shared__ unsigned short KS[16384];   // it0 strips (persist)

    int bid = blockIdx.x;
    int node = (bid & 7) + 8 * (bid >> 6);   // node's 8 blocks on one XCD
    int half = (bid >> 3) & 7;
    int x0 = half * 256;
    int t = threadIdx.x;
    int wv = t >> 6, ln = t & 63;
    int lr = ln & 15, lk = ln >> 4;

    const unsigned short* Asrc = Hbuf + (size_t)node * HSTRIDE;
    const unsigned short* Wsrc = Wbf + (size_t)node * 2048;
    int cg0 = pa[node * 32 + lk * 8];
    int cg1 = pa[node * 32 + lk * 8 + 4];

    unsigned short* strip0 = KS + wv * 2048;   // it=0, persistent
    unsigned short* strip1 = A1 + wv * 2048;   // it=1, transient

    // Z fragments: coalesced b128 from the precomputed panel (L2-hot)
    const unsigned short* Zp = Zpan + (size_t)node * 4096;
    short8 zv[8];
    #pragma unroll
    for (int mi = 0; mi < 8; mi++)
        zv[mi] = *(const short8*)(Zp + (size_t)(mi * 16 + lr) * 32 + lk * 8);
    // issue tile0 -> A0 early (hides under phase 1)
    #pragma unroll
    for (int i = 0; i < 4; i++) {
        int ch = i * 8 + wv;
        gload16(Asrc + ch * 512 + ln * 8, A0 + ch * 512);
    }
    // W fragments once (global, pre-swizzled)
    short8 aw[4];
    #pragma unroll
    for (int ks = 0; ks < 4; ks++)
        aw[ks] = *(const short8*)(Wsrc + lr * 128 + (((ks * 4 + lk) ^ (lr & 7)) * 8));

    // ---- phase 1: 2 col-groups -> bvAll + (strip0 | kreg1) + mean ----
    const float* Xb = X + (size_t)(x0 + wv * 32 + lr) * 256;
    const float* zsq_n = zsqg + node * 128;
    f32x4 xr0 = *(const f32x4*)(Xb + cg0);
    f32x4 xr1 = *(const f32x4*)(Xb + cg1);
    short8 bvAll[2][4];
    bf16x4 kreg1[8];
    f32x4 maccA[2];
    #pragma unroll
    for (int it = 0; it < 2; it++) {
        unsigned short* strip = it ? strip1 : strip0;
        float xs = 0.f;
        short8 xv = pack8(xr0, xr1, xs);
        xs += __shfl_xor(xs, 16);
        xs += __shfl_xor(xs, 32);
        if (it < 1) {   // next col-group = +16 rows of X
            xr0 = *(const f32x4*)(Xb + 4096 + cg0);
            xr1 = *(const f32x4*)(Xb + 4096 + cg1);
        }
        f32x4 dacc[8] = {};
        #pragma unroll
        for (int mi = 0; mi < 8; mi++)
            dacc[mi] = __builtin_amdgcn_mfma_f32_16x16x32_bf16(zv[mi], xv, dacc[mi], 0, 0, 0);
        #pragma unroll
        for (int mi = 0; mi < 8; mi++) {
            int mb = mi * 16 + lk * 4;
            f32x4 zs4 = *(const f32x4*)(zsq_n + mb);
            bf16x4 kv4;
            #pragma unroll
            for (int j = 0; j < 4; j++) {
                float sq = fmaxf(zs4[j] + xs - 2.0f * dacc[mi][j], 0.0f);
                kv4[j] = f2b(__expf(-0.5f * sq));
            }
            if (it) kreg1[mi] = kv4;
            *(bf16x4*)(strip + lr * 128 + (((mb >> 3) ^ (lr & 7)) * 8) + (mb & 7)) = kv4;
        }
        #pragma unroll
        for (int ks = 0; ks < 4; ks++)
            bvAll[it][ks] = *(const short8*)(strip + lr * 128 + (((ks * 4 + lk) ^ (lr & 7)) * 8));
        f32x4 m4 = {};
        #pragma unroll
        for (int ks = 0; ks < 4; ks++)
            m4 = __builtin_amdgcn_mfma_f32_16x16x32_bf16(aw[ks], bvAll[it][ks], m4, 0, 0, 0);
        maccA[it] = m4;
    }

    // ---- phase 2: 4 M-tiles, double-buffered, one barrier per tile ----
    float vout[4][2];
    #pragma unroll
    for (int tt = 0; tt < 4; tt++) {
        unsigned short* cbuf = (tt & 1) ? A1 : A0;
        __syncthreads();   // tile tt landed; prev reads (incl. strip1) done
        if (tt < 3) {
            const unsigned short* ns = Asrc + (size_t)(tt + 1) * 16384;
            unsigned short* nb = (tt & 1) ? A0 : A1;
            #pragma unroll
            for (int i = 0; i < 4; i++) {
                int ch = i * 8 + wv;
                gload16(ns + ch * 512 + ln * 8, nb + ch * 512);
            }
        }
        float ssum[2] = {0.f, 0.f};
        __builtin_amdgcn_s_setprio(1);
        #pragma unroll
        for (int mi = 0; mi < 8; mi++) {
            int r = mi * 16 + lr;
            int mb = mi * 16 + lk * 4;
            f32x4 a4[2] = {};
            #pragma unroll
            for (int ks = 0; ks < 4; ks++) {
                short8 av = *(const short8*)(cbuf + r * 128 + (((ks * 4 + lk) ^ (r & 7)) * 8));
                #pragma unroll
                for (int it = 0; it < 2; it++)
                    a4[it] = __builtin_amdgcn_mfma_f32_16x16x32_bf16(av, bvAll[it][ks], a4[it], 0, 0, 0);
            }
            bf16x4 k0 = *(const bf16x4*)(strip0 + lr * 128 + (((mb >> 3) ^ (lr & 7)) * 8) + (mb & 7));
            #pragma unroll
            for (int j = 0; j < 4; j++) {
                ssum[0] += a4[0][j] * b2f(k0[j]);
                ssum[1] += a4[1][j] * b2f(kreg1[mi][j]);
            }
        }
        __builtin_amdgcn_s_setprio(0);
        #pragma unroll
        for (int it = 0; it < 2; it++) {
            float sv = ssum[it];
            sv += __shfl_xor(sv, 16);
            sv += __shfl_xor(sv, 32);
            vout[tt][it] = sv;
        }
    }

    // ---- output ----
    if (lk == 0) {
        #pragma unroll
        for (int it = 0; it < 2; it++) {
            int x = x0 + wv * 32 + it * 16 + lr;
            f32x4 mv, vv;
            #pragma unroll
            for (int j = 0; j < 4; j++) {
                mv[j] = maccA[it][j];
                vv[j] = 1.0f + vout[j][it];
            }
            *(f32x4*)(out + (size_t)x * 256 + node * 4) = mv;
            *(f32x4*)(out + 524288 + (size_t)x * 256 + node * 4) = vv;
        }
    }
}

extern "C" void kernel_launch(void* const* d_in, const int* in_sizes, int n_in,
                              void* d_out, int out_size, void* d_ws, size_t ws_size,
                              hipStream_t stream) {
    const float* X = (const float*)d_in[0];
    const float* Z = (const float*)d_in[1];
    const float* qmu = (const float*)d_in[2];
    const float* qsqrt = (const float*)d_in[3];
    const int* pa = (const int*)d_in[4];
    float* out = (float*)d_out;

    char* ws = (char*)d_ws;
    size_t off = 0;
    unsigned short* Wbf = (unsigned short*)(ws + off);   off += 131072ull * 2;   // 256 KB
    unsigned short* Hbuf = (unsigned short*)(ws + off);  off += 4194304ull * 2;  // 8 MB
    unsigned short* Zpan = (unsigned short*)(ws + off);  off += 262144ull * 2;   // 512 KB
    float* zsqg = (float*)(ws + off);                    off += 8192ull * 4;     // 32 KB

    k_nsgt<<<256, 512, 0, stream>>>(Z, pa, qmu, qsqrt, Wbf, Hbuf, Zpan, zsqg);
    k_main<<<512, 512, 0, stream>>>(X, Zpan, zsqg, pa, Hbuf, Wbf, out);
}